// Round 12
// baseline (350.924 us; speedup 1.0000x reference)
//
#include <hip/hip_runtime.h>
#include <hip/hip_fp16.h>
#include <math.h>

#define HW 65536            // 256*256
#define CHW 4194304         // 64*HW  (NHWC elements per batch)
#define BCHW 16777216
#define HW2 262144          // 512*512
#define TS 325              // tile pad stride (px) to break LDS conflicts

typedef _Float16 half8 __attribute__((ext_vector_type(8)));
typedef _Float16 half2v __attribute__((ext_vector_type(2)));
typedef float f32x4 __attribute__((ext_vector_type(4)));
typedef float f32x2 __attribute__((ext_vector_type(2)));

// XCD-locality tile mapping. Linearized wg id mod 8 == ibx&7 == XCD under
// round-robin dispatch. Map each XCD to 2 full tile-rows. Bijection 16x16.
__device__ __forceinline__ void swz16(int ibx, int iby, int& ox, int& oy) {
    oy = ((ibx & 7) << 1) | (ibx >> 3);
    ox = iby;
}

// chans layout: [8 layers][8 parts][4 b][64]  (parts indexed by ibx&7 = XCD)
#define CH_L 2048           // floats per layer (8 parts x 256)

// ---------------------------------------------------------------- ternarize
// mode: 0 = float only; 1 = + half linear; 2 = + half dw-transpose [tap][ci];
//       3 = + float transposed [k][64] (shallow conv, packed-f32 layout)
// block 21: zero chans + prepare recon Wt halves
struct TernDesc { const float* src; float* dst; __half* dsth; float* dstT; int n; int mode; };
struct TernArgs { TernDesc d[21]; };

__global__ __launch_bounds__(256) void ternarize_kernel(TernArgs args, float* __restrict__ chans,
                                                        const float* __restrict__ rw,
                                                        __half* __restrict__ rwh) {
    const int t = threadIdx.x;
    if (blockIdx.x == 21) {
        for (int i = t; i < 16384; i += 256) chans[i] = 0.f;
        for (int i = t; i < 10368; i += 256) {
            const int row = i / 72, ci = i - row * 72;
            const int tap = row >> 4, n = row & 15;
            rwh[i] = __float2half((ci < 64 && n < 12) ? rw[n * 576 + ci * 9 + tap] : 0.f);
        }
        return;
    }
    __shared__ float red[256];
    __shared__ float bc[2];
    TernDesc td = args.d[blockIdx.x];
    const int n = td.n;
    float s = 0.f;
    for (int i = t; i < n; i += 256) s += fabsf(td.src[i]);
    red[t] = s; __syncthreads();
    for (int k = 128; k > 0; k >>= 1) { if (t < k) red[t] += red[t + k]; __syncthreads(); }
    if (t == 0) bc[0] = 0.75f * red[0] / (float)n;
    __syncthreads();
    const float delta = bc[0];
    float s1 = 0.f, c1 = 0.f;
    for (int i = t; i < n; i += 256) {
        float a = fabsf(td.src[i]);
        if (a > delta) { s1 += a; c1 += 1.f; }
    }
    __syncthreads();
    red[t] = s1; __syncthreads();
    for (int k = 128; k > 0; k >>= 1) { if (t < k) red[t] += red[t + k]; __syncthreads(); }
    float sum1 = red[0];
    __syncthreads();
    red[t] = c1; __syncthreads();
    for (int k = 128; k > 0; k >>= 1) { if (t < k) red[t] += red[t + k]; __syncthreads(); }
    if (t == 0) bc[1] = sum1 / fmaxf(red[0], 1.f);
    __syncthreads();
    const float alpha = bc[1];
    for (int i = t; i < n; i += 256) {
        float w = td.src[i];
        const float q = (fabsf(w) > delta) ? ((w > 0.f) ? alpha : -alpha) : 0.f;
        td.dst[i] = q;
        if (td.mode == 1) td.dsth[i] = __float2half(q);
        else if (td.mode == 2) {
            const int ci = i / 9, tap = i - ci * 9;
            td.dsth[tap * 64 + ci] = __float2half(q);
        } else if (td.mode == 3) {
            const int co = i / 27, k = i - co * 27;
            td.dstT[k * 64 + co] = q;
        }
    }
}

// ---------------------------------------------------------------- y kernel: GAP->fc1->relu->fc2->sigmoid once per (expert, b)
__global__ __launch_bounds__(64) void y_kernel(const float* __restrict__ chans,
                                               const float* __restrict__ fc1b,
                                               const float* __restrict__ fc2b,
                                               __half* __restrict__ ysm_g,
                                               int ebase, int lbase) {
    __shared__ float csum[64];
    __shared__ float hid[16];
    const int t = threadIdx.x;
    const int e = ebase + (blockIdx.x >> 2), b = blockIdx.x & 3;
    const int li = e * 2 + lbase;
    {
        const float* cp = chans + li * CH_L + b * 64 + t;
        float s = 0.f;
#pragma unroll
        for (int p = 0; p < 8; p++) s += cp[p * 256];
        csum[t] = s;
    }
    __syncthreads();
    if (t < 16) {
        const float* fc1 = fc1b + li * 1024;
        float s = 0.f;
        for (int ci = 0; ci < 64; ci++) s = fmaf(fc1[t * 64 + ci], csum[ci], s);
        hid[t] = fmaxf(s, 0.f) * (1.f / 65536.f);
    }
    __syncthreads();
    {
        const float* fc2 = fc2b + li * 1024;
        float s = 0.f;
#pragma unroll
        for (int j = 0; j < 16; j++) s = fmaf(fc2[t * 16 + j], hid[j], s);
        ysm_g[li * 256 + b * 64 + t] = __float2half(1.f / (1.f + expf(-s)));
    }
}

// ---------------------------------------------------------------- fused shallow conv + texture encoder + router (512 thr)
// Shallow conv processes channel PAIRS via float2 (v_pk_fma_f32): weights
// arrive pre-transposed [k][64] (qshT). xs staged as f32x2 (pairs provably
// all-in/all-out of bounds: even column base). Bit-identical math.
__global__ __launch_bounds__(512, 6) void shallow_router_kernel(
    const float* __restrict__ x,
    const float* __restrict__ qshT, const float* __restrict__ shb,
    const float* __restrict__ qtdw, const float* __restrict__ tdwb,
    const float* __restrict__ qtpw, const float* __restrict__ tpwb,
    const float* __restrict__ rw,   const float* __restrict__ rbias,
    __half* __restrict__ feat_h, int* __restrict__ top) {
    __shared__ __align__(16) float xs[1200];          // [3][20][20]
    __shared__ __align__(16) float feats[324 * 36];   // [halo px][ch pad36]
    const int t = threadIdx.x;
    const int b = blockIdx.z;
    const int h0 = blockIdx.y * 16, w0 = blockIdx.x * 16;
    const float* xb = x + (size_t)b * 3 * HW;

    for (int i2 = t; i2 < 600; i2 += 512) {
        const int ci = i2 / 200, rem = i2 - ci * 200;
        const int ry = rem / 10, ux = rem - ry * 10;
        const int hh = h0 + ry - 2, wc = w0 + ux * 2 - 2;
        f32x2 v = {0.f, 0.f};
        if (hh >= 0 && hh < 256 && wc >= 0 && wc < 256)
            v = *(const f32x2*)&xb[ci * HW + hh * 256 + wc];
        *(f32x2*)&xs[ci * 400 + ry * 20 + ux * 2] = v;
    }
    float tex[8] = {0, 0, 0, 0, 0, 0, 0, 0};
    __half* fhb = feat_h + (size_t)b * CHW;
    __syncthreads();

    for (int pass = 0; pass < 2; pass++) {
        const int c0 = pass * 32;
        if (pass) __syncthreads();
        if (t < 324) {
            const int ry = t / 18, rx = t - ry * 18;
            float patch[27];
#pragma unroll
            for (int ci = 0; ci < 3; ci++)
#pragma unroll
                for (int dy = 0; dy < 3; dy++)
#pragma unroll
                    for (int dx = 0; dx < 3; dx++)
                        patch[ci * 9 + dy * 3 + dx] = xs[ci * 400 + (ry + dy) * 20 + rx + dx];
            for (int g = 0; g < 16; g++) {       // channel pairs (packed f32)
                const int co = c0 + g * 2;       // GLOBAL channel for weights
                f32x2 a2 = { shb[co], shb[co + 1] };
#pragma unroll
                for (int k = 0; k < 27; k++) {
                    const f32x2 w2 = *(const f32x2*)&qshT[k * 64 + co];
                    const f32x2 p2 = { patch[k], patch[k] };
                    a2 = __builtin_elementwise_fma(p2, w2, a2);
                }
                feats[t * 36 + g * 2]     = fmaxf(a2[0], 0.f);   // LOCAL LDS offset
                feats[t * 36 + g * 2 + 1] = fmaxf(a2[1], 0.f);
            }
        }
        __syncthreads();
        if (t < 256) {
            const int iy = t >> 4, ix = t & 15;
            for (int g = 0; g < 8; g++) {      // 4 channels per group, order preserved
                const int cl = g * 4;          // LOCAL channel offset in LDS row
                const int cb = c0 + cl;        // global channel for weights
                f32x4 o4;
#pragma unroll
                for (int c = 0; c < 4; c++) o4[c] = tdwb[cb + c];
#pragma unroll
                for (int dy = 0; dy < 3; dy++) {
                    const float* rowp = &feats[((iy + dy) * 18 + ix) * 36 + cl];
                    const f32x4 r0 = *(const f32x4*)&rowp[0];
                    const f32x4 r1 = *(const f32x4*)&rowp[36];
                    const f32x4 r2 = *(const f32x4*)&rowp[72];
                    f32x4 w0, w1, w2;
#pragma unroll
                    for (int c = 0; c < 4; c++) {
                        w0[c] = qtdw[(cb + c) * 9 + dy * 3];
                        w1[c] = qtdw[(cb + c) * 9 + dy * 3 + 1];
                        w2[c] = qtdw[(cb + c) * 9 + dy * 3 + 2];
                    }
                    // same chain as scalar: dx=2, then dx=1, then dx=0
                    o4 = __builtin_elementwise_fma(r2, w2, o4);
                    o4 = __builtin_elementwise_fma(r1, w1, o4);
                    o4 = __builtin_elementwise_fma(r0, w0, o4);
                }
#pragma unroll
                for (int c = 0; c < 4; c++) {
                    const float tc = fmaxf(o4[c], 0.f);
#pragma unroll
                    for (int j = 0; j < 8; j++)
                        tex[j] = fmaf(qtpw[j * 64 + cb + c], tc, tex[j]);
                }
            }
        } else {
            for (int id = t - 256; id < 1024; id += 256) {
                const int p = id >> 2, cg = id & 3;
                const int py = p >> 4, px = p & 15;
                const float* fp = &feats[((py + 1) * 18 + px + 1) * 36 + cg * 8];
                half8 pk;
#pragma unroll
                for (int j = 0; j < 8; j++) pk[j] = (_Float16)fp[j];
                *(half8*)&fhb[((size_t)((h0 + py) * 256 + w0 + px)) * 64 + c0 + cg * 8] = pk;
            }
        }
    }
    if (t < 256) {
        const int iy = t >> 4, ix = t & 15;
        float sgm[8];
#pragma unroll
        for (int j = 0; j < 8; j++) sgm[j] = 1.f / (1.f + expf(-(tex[j] + tpwb[j])));
        float best = -1e30f; int bi = 0;
#pragma unroll
        for (int e = 0; e < 4; e++) {
            float v = rbias[e];
#pragma unroll
            for (int j = 0; j < 8; j++) v = fmaf(rw[e * 8 + j], sgm[j], v);
            if (v > best) { best = v; bi = e; }     // first max (jnp.argmax)
        }
        top[(size_t)b * HW + (h0 + iy) * 256 + w0 + ix] = bi;
    }
}

// ---------------------------------------------------------------- expert block: 512 threads (r1 structure)
// APPLY: no pre-staging barrier -- routed A-store checks topg DIRECTLY
// (L2-resident), so the 12 staging loads issue at block start and overlap
// the weight-staging prologue. topsm (LDS) is only consumed in the epilogue,
// ordered by the post-staging barrier.
template <bool APPLY>
__global__ __launch_bounds__(512, 4) void expert_block_kernel(
    const __half* __restrict__ in,
    const __half* __restrict__ qdwh_b, const float* __restrict__ dwb_b,
    const __half* __restrict__ qpwh_b, const float* __restrict__ pwb_b,
    __half* __restrict__ out_b, float* __restrict__ chans_b,
    const __half* __restrict__ ysm_g,
    const __half* __restrict__ F, __half* __restrict__ Aap,
    const int* __restrict__ topg, int ebase, int bshift) {
    __shared__ __align__(16) __half tile[8 * TS * 8];    // 41600 B; obuf/csb alias
    __shared__ __align__(16) __half wT[64 * 72];         // [co][ci pad72] 9216 B
    __shared__ __align__(16) __half wdwh[576];           // [tap][ci] 1152 B
    __shared__ __align__(16) _Float16 bdwh[64];
    __shared__ float bpw[64];
    __shared__ unsigned char topsm[256];
    const int t = threadIdx.x;
    const int z = blockIdx.z;
    const int b = z >> bshift, sub = z & ((1 << bshift) - 1);
    const int expert = ebase + sub;
    const int layer = expert * 2 + (APPLY ? 1 : 0);
    const int part = blockIdx.x & 7;                     // == XCD under round-robin
    const float* dwb = dwb_b + layer * 64;
    const float* pwb = pwb_b + layer * 64;
    float* chansum = chans_b + layer * CH_L + part * 256 + b * 64;
    int bx, by; swz16(blockIdx.x, blockIdx.y, bx, by);
    const int h0 = by * 16, w0 = bx * 16;

    const int* tb = topg ? (topg + (size_t)b * HW) : nullptr;
    {   // pw weights: 4096 halves = 512 threads x 1 half8
        const half8 w8 = *(const half8*)&qpwh_b[layer * 4096 + t * 8];
        *(half8*)&wT[(t >> 3) * 72 + (t & 7) * 8] = w8;
    }
    if (t < 72) *(half8*)&wdwh[t * 8] = *(const half8*)&qdwh_b[layer * 576 + t * 8];
    if (t < 64) { bdwh[t] = (_Float16)dwb[t]; bpw[t] = pwb[t]; }

    half8 y8h = {};
    if (APPLY) {
        if (t < 256)
            topsm[t] = (unsigned char)tb[(h0 + (t >> 4)) * 256 + w0 + (t & 15)];
        y8h = *(const half8*)&ysm_g[(expert * 2) * 256 + b * 64 + (t & 7) * 8];
        // no barrier: staging uses direct topg loads for routing
    }

    const __half* ib = (APPLY ? in + (size_t)sub * BCHW : in) + (size_t)b * CHW;
    const __half* Fb = APPLY ? (F + (size_t)b * CHW) : nullptr;
    __half* Ab = APPLY ? (Aap + (size_t)b * CHW) : nullptr;
    __half* ob = APPLY ? (out_b + (size_t)b * CHW)
                       : (out_b + (size_t)sub * BCHW + (size_t)b * CHW);

    // staging, force-unrolled: 5 full iterations + 32-thread tail
#pragma unroll
    for (int s = 0; s < 6; s++) {
        if (s < 5 || t < 32) {
            const int i = t + (s << 9);
            const int cg = i & 7;
            const int rem = i >> 3;            // 0..323
            const int ry = rem / 18, rx = rem - ry * 18;
            const int hh = h0 + ry - 1, ww = w0 + rx - 1;
            half8 v = {};
            if (hh >= 0 && hh < 256 && ww >= 0 && ww < 256) {
                const size_t off = (size_t)(hh * 256 + ww) * 64 + cg * 8;
                v = *(const half8*)&ib[off];
                if (APPLY) {
                    half8 f = *(const half8*)&Fb[off];
                    v = __builtin_elementwise_fma(v, y8h, f);
                    if (ry >= 1 && ry <= 16 && rx >= 1 && rx <= 16 &&
                        tb[hh * 256 + ww] == expert)
                        *(half8*)&Ab[off] = v;
                }
            }
            *(half8*)&tile[(cg * TS + rem) * 8] = v;
        }
    }
    __syncthreads();

    const int lane = t & 63, wv = t >> 6;      // 8 waves, 2 rows each
    const int l15 = lane & 15, quad = lane >> 4;
    f32x4 acc[2][4];
#pragma unroll
    for (int i = 0; i < 2; i++)
#pragma unroll
        for (int j = 0; j < 4; j++) acc[i][j] = (f32x4){0.f, 0.f, 0.f, 0.f};

#pragma unroll
    for (int kh = 0; kh < 2; kh++) {
        const int cgk = kh * 4 + quad;
        half8 bf[4];
#pragma unroll
        for (int ct = 0; ct < 4; ct++)
            bf[ct] = *(const half8*)&wT[(ct * 16 + l15) * 72 + kh * 32 + quad * 8];
        half8 wv9[9];
#pragma unroll
        for (int tap = 0; tap < 9; tap++)
            wv9[tap] = *(const half8*)&wdwh[tap * 64 + kh * 32 + quad * 8];
        const half8 biash = *(const half8*)&bdwh[kh * 32 + quad * 8];
        // row-shared tap loads: rows wv*2..wv*2+3 (T=0 uses 0..2, T=1 uses 1..3)
        half8 xr[9];
#pragma unroll
        for (int dy = 0; dy < 3; dy++)
#pragma unroll
            for (int dx = 0; dx < 3; dx++)
                xr[dy * 3 + dx] = *(const half8*)&tile[(cgk * TS + (wv * 2 + dy) * 18 + (l15 + dx)) * 8];
#pragma unroll
        for (int T = 0; T < 2; T++) {
            if (T) {
#pragma unroll
                for (int q2 = 0; q2 < 6; q2++) xr[q2] = xr[q2 + 3];
#pragma unroll
                for (int dx = 0; dx < 3; dx++)
                    xr[6 + dx] = *(const half8*)&tile[(cgk * TS + (wv * 2 + 3) * 18 + (l15 + dx)) * 8];
            }
            // packed fp16 depthwise accumulate: 4x v_pk_fma_f16 per tap, no cvts
            half8 o8 = biash;
#pragma unroll
            for (int tap = 0; tap < 9; tap++)
                o8 = __builtin_elementwise_fma(xr[tap], wv9[tap], o8);
            const half8 zz = {};
            const half8 a = __builtin_elementwise_max(o8, zz);
#pragma unroll
            for (int ct = 0; ct < 4; ct++)
                acc[T][ct] = __builtin_amdgcn_mfma_f32_16x16x32_f16(a, bf[ct], acc[T][ct], 0, 0, 0);
        }
    }
    __syncthreads();   // tile reads done; alias obuf + csb onto tile

    __half* obuf = tile;                              // bytes 0..17407
    float* csb = (float*)((char*)tile + 20480);       // [8][64] floats
    __half* myo = &obuf[wv * 1088];
    float cs[4] = {0.f, 0.f, 0.f, 0.f};
    const int pxa = lane >> 3;
#pragma unroll
    for (int T = 0; T < 2; T++) {
        const int py_loc = wv * 2 + T;
#pragma unroll
        for (int ct = 0; ct < 4; ct++) {
            const float bv = bpw[ct * 16 + l15];
#pragma unroll
            for (int r = 0; r < 4; r++) {
                const float v = acc[T][ct][r] + bv;
                cs[ct] += v;
                myo[(quad * 4 + r) * 68 + ct * 16 + l15] = __float2half(v);
            }
        }
        const int py = h0 + py_loc;
        const size_t base = (size_t)(py * 256 + w0) * 64;
        half8 v0 = *(const half8*)&myo[pxa * 68 + (lane & 7) * 8];
        half8 v1 = *(const half8*)&myo[(8 + pxa) * 68 + (lane & 7) * 8];
        if (!APPLY || topsm[py_loc * 16 + pxa] == expert)
            *(half8*)&ob[base + lane * 8] = v0;
        if (!APPLY || topsm[py_loc * 16 + 8 + pxa] == expert)
            *(half8*)&ob[base + (lane + 64) * 8] = v1;
    }
#pragma unroll
    for (int ct = 0; ct < 4; ct++) {
        float s = cs[ct];
        s += __shfl_xor(s, 16);
        s += __shfl_xor(s, 32);
        if (quad == 0) csb[wv * 64 + ct * 16 + l15] = s;
    }
    __syncthreads();
    if (t < 64) {
        float s = 0.f;
#pragma unroll
        for (int w = 0; w < 8; w++) s += csb[w * 64 + t];
        atomicAdd(&chansum[t], s);
    }
}

// ---------------------------------------------------------------- bilinear x2 upsample from an 18x18 LDS region
__device__ __forceinline__ float bilin_lds(const float* __restrict__ xr,
                                           int h0, int w0, int h, int w, int r1, int r2) {
    int hlo, hhi; float wrr;
    if (r1 == 0) { hlo = h - 1; hhi = h;     wrr = 0.25f; }
    else         { hlo = h;     hhi = h + 1; wrr = 0.75f; }
    if (hlo < 0)   { hlo = 0;   wrr = 0.f; }
    if (hhi > 255) { hhi = 255; wrr = 1.f; }
    int wlo, whi; float wcc;
    if (r2 == 0) { wlo = w - 1; whi = w;     wcc = 0.25f; }
    else         { wlo = w;     whi = w + 1; wcc = 0.75f; }
    if (wlo < 0)   { wlo = 0;   wcc = 0.f; }
    if (whi > 255) { whi = 255; wcc = 1.f; }
    const int rl = hlo - (h0 - 1), rh = hhi - (h0 - 1);
    const int cl = wlo - (w0 - 1), ch = whi - (w0 - 1);
    const float a = xr[rl * 18 + cl] * wcc + xr[rl * 18 + ch] * (1.f - wcc);
    const float b = xr[rh * 18 + cl] * wcc + xr[rh * 18 + ch] * (1.f - wcc);
    return a * wrr + b * (1.f - wrr);
}

// ---------------------------------------------------------------- recon (512 thr) fused select; y1 precomputed; x + top staged in LDS
__global__ __launch_bounds__(512, 4) void recon_kernel(const __half* __restrict__ Bv,
                                                       const __half* __restrict__ Aap,
                                                       const int* __restrict__ topg,
                                                       const __half* __restrict__ ysm_g,
                                                       const __half* __restrict__ rwh,  // [9*16][72] halves
                                                       const float* __restrict__ rbias,
                                                       const float* __restrict__ x,
                                                       __half* __restrict__ srh) {
    __shared__ __align__(16) __half tile[8 * TS * 8];     // 41600 B
    __shared__ __align__(16) __half Wt[9 * 16 * 72];      // 20736 B
    __shared__ float xls[3 * 324];                        // [3][18][18] clamped x region
    __shared__ int topls[324];                            // top halo (OOB -> 0)
    __shared__ float bsm12[12];
    __shared__ __align__(16) _Float16 ysmh[4][64];
    const int t = threadIdx.x;
    const int b = blockIdx.z;
    int bx, by; swz16(blockIdx.x, blockIdx.y, bx, by);
    const int h0 = by * 16, w0 = bx * 16;
    const int* tb = topg + (size_t)b * HW;

    for (int i = t; i < 1296; i += 512)
        *(half8*)&Wt[i * 8] = *(const half8*)&rwh[i * 8];
    {   // stage clamped 18x18x3 x region (coalesced, 2 rounds)
        const float* xb3 = x + (size_t)b * 3 * HW;
        for (int i = t; i < 972; i += 512) {
            const int ci = i / 324, rem = i - ci * 324;
            const int ry = rem / 18, rx = rem - ry * 18;
            const int gh = min(max(h0 - 1 + ry, 0), 255);
            const int gw = min(max(w0 - 1 + rx, 0), 255);
            xls[i] = xb3[ci * HW + gh * 256 + gw];
        }
    }
    if (t < 324) {  // stage top halo once (8 channel groups reuse it)
        const int ry = t / 18, rx = t - ry * 18;
        const int hh = h0 + ry - 1, ww = w0 + rx - 1;
        topls[t] = (hh >= 0 && hh < 256 && ww >= 0 && ww < 256) ? tb[hh * 256 + ww] : 0;
    }
    if (t < 12) bsm12[t] = rbias[t];
    if (t >= 480) {   // y1 for the 4 experts (precomputed by y_kernel)
        const int u = t - 480, e = u >> 3;
        *(half8*)&ysmh[e][(u & 7) * 8] =
            *(const half8*)&ysm_g[(e * 2 + 1) * 256 + b * 64 + (u & 7) * 8];
    }
    __syncthreads();    // ysmh + Wt + xls + topls ready

    const __half* bb = Bv + (size_t)b * CHW;
    const __half* ab = Aap + (size_t)b * CHW;

#pragma unroll
    for (int s = 0; s < 6; s++) {
        if (s < 5 || t < 32) {
            const int i = t + (s << 9);
            const int cg = i & 7;
            const int rem = i >> 3;
            const int ry = rem / 18, rx = rem - ry * 18;
            const int hh = h0 + ry - 1, ww = w0 + rx - 1;
            half8 v = {};
            if (hh >= 0 && hh < 256 && ww >= 0 && ww < 256) {
                const size_t off = (size_t)(hh * 256 + ww) * 64 + cg * 8;
                half8 bv8 = *(const half8*)&bb[off];
                half8 av8 = *(const half8*)&ab[off];
                const int e = topls[rem];
                half8 yv = *(const half8*)&ysmh[e][cg * 8];
                v = __builtin_elementwise_fma(bv8, yv, av8);
            }
            *(half8*)&tile[(cg * TS + rem) * 8] = v;
        }
    }
    __syncthreads();

    const int lane = t & 63, wvi = t >> 6;
    const int l15 = lane & 15, quad = lane >> 4;
    f32x4 acc[2];
#pragma unroll
    for (int i = 0; i < 2; i++) acc[i] = (f32x4){0.f, 0.f, 0.f, 0.f};

#pragma unroll
    for (int kh = 0; kh < 2; kh++) {
        const int cgk = kh * 4 + quad;
        half8 bf[9];
#pragma unroll
        for (int tap = 0; tap < 9; tap++)
            bf[tap] = *(const half8*)&Wt[(tap * 16 + l15) * 72 + kh * 32 + quad * 8];
        // row-shared tap loads
        half8 xr[9];
#pragma unroll
        for (int dy = 0; dy < 3; dy++)
#pragma unroll
            for (int dx = 0; dx < 3; dx++)
                xr[dy * 3 + dx] = *(const half8*)&tile[(cgk * TS + (wvi * 2 + dy) * 18 + (l15 + dx)) * 8];
#pragma unroll
        for (int T = 0; T < 2; T++) {
            if (T) {
#pragma unroll
                for (int q2 = 0; q2 < 6; q2++) xr[q2] = xr[q2 + 3];
#pragma unroll
                for (int dx = 0; dx < 3; dx++)
                    xr[6 + dx] = *(const half8*)&tile[(cgk * TS + (wvi * 2 + 3) * 18 + (l15 + dx)) * 8];
            }
#pragma unroll
            for (int tap = 0; tap < 9; tap++)
                acc[T] = __builtin_amdgcn_mfma_f32_16x16x32_f16(xr[tap], bf[tap], acc[T], 0, 0, 0);
        }
    }
    if (l15 < 12) {
        const int c = l15 >> 2, r1 = (l15 >> 1) & 1, r2 = l15 & 1;
        const float* xreg = &xls[c * 324];
        const float bv = bsm12[l15];
        __half* sb = srh + ((size_t)b * 3 + c) * HW2;
#pragma unroll
        for (int T = 0; T < 2; T++) {
            const int py = h0 + wvi * 2 + T;
#pragma unroll
            for (int r = 0; r < 4; r++) {
                const int wglob = w0 + quad * 4 + r;
                const float xu = bilin_lds(xreg, h0, w0, py, wglob, r1, r2);
                sb[(2 * py + r1) * 512 + 2 * wglob + r2] = __float2half(acc[T][r] + bv + xu);
            }
        }
    }
}

// ---------------------------------------------------------------- fused refinement: out = sr + conv2(relu(conv1(sr))); fp16 sr in
// sr staging via half2 (pairs are all-in/all-out of bounds: even column base)
__global__ __launch_bounds__(256) void ref_fused_kernel(const __half* __restrict__ in,  // sr half [4][3][512][512]
                                                        const float* __restrict__ q1,
                                                        const float* __restrict__ b1,
                                                        const float* __restrict__ q2,
                                                        const float* __restrict__ b2,
                                                        float* __restrict__ outp) {
    __shared__ float srs[1200];       // [3][20][20] halo ±2
    __shared__ float t1s[3 * 324];    // [3][18][18] halo ±1
    __shared__ float w1[81], w2[81];
    __shared__ float bb1[3], bb2[3];
    const int t = threadIdx.y * 16 + threadIdx.x;
    const int b = blockIdx.z;
    const int h0 = blockIdx.y * 16, w0 = blockIdx.x * 16;
    if (t < 81) { w1[t] = q1[t]; w2[t] = q2[t]; }
    if (t < 3)  { bb1[t] = b1[t]; bb2[t] = b2[t]; }
    for (int i2 = t; i2 < 600; i2 += 256) {
        const int ci = i2 / 200, rem = i2 - ci * 200;
        const int ry = rem / 10, ux = rem - ry * 10;
        const int hh = h0 + ry - 2, wc = w0 + ux * 2 - 2;
        float v0 = 0.f, v1 = 0.f;
        if (hh >= 0 && hh < 512 && wc >= 0 && wc < 512) {
            const half2v p = *(const half2v*)&in[((size_t)b * 3 + ci) * HW2 + hh * 512 + wc];
            v0 = (float)p[0]; v1 = (float)p[1];
        }
        srs[ci * 400 + ry * 20 + ux * 2] = v0;
        srs[ci * 400 + ry * 20 + ux * 2 + 1] = v1;
    }
    __syncthreads();
    for (int p = t; p < 324; p += 256) {
        const int ry = p / 18, rx = p - ry * 18;
        const int ih = h0 + ry - 1, iw = w0 + rx - 1;
        const bool valid = (ih >= 0 && ih < 512 && iw >= 0 && iw < 512);
#pragma unroll
        for (int o = 0; o < 3; o++) {
            float a = 0.f;
#pragma unroll
            for (int ci = 0; ci < 3; ci++) {
                const float* wp = &w1[o * 27 + ci * 9];
                const float* sp = &srs[ci * 400 + ry * 20 + rx];
#pragma unroll
                for (int ky = 0; ky < 3; ky++)
#pragma unroll
                    for (int kx = 0; kx < 3; kx++)
                        a = fmaf(sp[ky * 20 + kx], wp[ky * 3 + kx], a);
            }
            t1s[o * 324 + p] = valid ? fmaxf(a + bb1[o], 0.f) : 0.f;
        }
    }
    __syncthreads();
    const int ty = threadIdx.y, tx = threadIdx.x;
#pragma unroll
    for (int o = 0; o < 3; o++) {
        float a = 0.f;
#pragma unroll
        for (int ci = 0; ci < 3; ci++) {
            const float* wp = &w2[o * 27 + ci * 9];
            const float* tp = &t1s[ci * 324 + ty * 18 + tx];
#pragma unroll
            for (int ky = 0; ky < 3; ky++)
#pragma unroll
                for (int kx = 0; kx < 3; kx++)
                    a = fmaf(tp[ky * 18 + kx], wp[ky * 3 + kx], a);
        }
        const float v = a + bb2[o] + srs[o * 400 + (ty + 2) * 20 + tx + 2];
        outp[((size_t)b * 3 + o) * HW2 + (h0 + ty) * 512 + w0 + tx] = v;
    }
}

// ---------------------------------------------------------------- launcher
extern "C" void kernel_launch(void* const* d_in, const int* in_sizes, int n_in,
                              void* d_out, int out_size, void* d_ws, size_t ws_size,
                              hipStream_t stream) {
    const float* x         = (const float*)d_in[0];
    const float* shallow_w = (const float*)d_in[1];
    const float* shallow_b = (const float*)d_in[2];
    const float* tex_dw_w  = (const float*)d_in[3];
    const float* tex_dw_b  = (const float*)d_in[4];
    const float* tex_pw_w  = (const float*)d_in[5];
    const float* tex_pw_b  = (const float*)d_in[6];
    const float* router_w  = (const float*)d_in[7];
    const float* router_b  = (const float*)d_in[8];
    const float* exp_dw_w  = (const float*)d_in[9];
    const float* exp_dw_b  = (const float*)d_in[10];
    const float* exp_pw_w  = (const float*)d_in[11];
    const float* exp_pw_b  = (const float*)d_in[12];
    const float* exp_fc1   = (const float*)d_in[13];
    const float* exp_fc2   = (const float*)d_in[14];
    const float* recon_w   = (const float*)d_in[15];
    const float* recon_b   = (const float*)d_in[16];
    const float* ref1_w    = (const float*)d_in[17];
    const float* ref1_b    = (const float*)d_in[18];
    const float* ref2_w    = (const float*)d_in[19];
    const float* ref2_b    = (const float*)d_in[20];

    // mode: merged (all 4 experts per dispatch, 4 A-slots) if workspace allows
    const size_t need_merged = 237000000ULL;
    const bool merged = (ws_size >= need_merged);
    const int nslot = merged ? 4 : 2;

    __half* feat_h = (__half*)d_ws;                      // 32 MB
    __half* A4     = feat_h + BCHW;                      // nslot x 32 MB
    __half* Bv_sh  = A4 + (size_t)nslot * BCHW;          // 32 MB, routed-shared
    __half* Aap_sh = Bv_sh + BCHW;                       // 32 MB, routed-shared
    int*    top    = (int*)(Aap_sh + BCHW);              // 1 MB
    __half* q_edw_h = (__half*)(top + 262144);           // 8*576 halves (16B aligned)
    __half* q_epw_h = q_edw_h + 4608;                    // 8*4096 halves
    __half* rwh     = q_epw_h + 32768;                   // 10368 halves (recon Wt)
    __half* ysm_g   = rwh + 10368;                       // 2048 halves (y per layer,b)
    float*  qb     = (float*)(ysm_g + 2048);
    float*  q_sh   = qb;                 // 1728 (linear float, unused by kernels)
    float*  q_tdw  = q_sh + 1728;        // 576
    float*  q_tpw  = q_tdw + 576;        // 512
    float*  q_edw  = q_tpw + 512;        // 8*576 (float copy, unused by kernels)
    float*  q_epw  = q_edw + 4608;       // 8*4096 (float copy, unused by kernels)
    float*  q_r1   = q_epw + 32768;      // 81
    float*  q_r2   = q_r1 + 81;          // 81
    float*  chans  = q_r2 + 81;          // 8 layers x 8 parts x 256 = 16384
    float*  qshT   = chans + 16384;      // 27*64 transposed shallow weights
    __half* srh    = (__half*)A4;        // 25 MB as half (A4 dead after last APPLY)

    TernArgs ta;
    ta.d[0] = { shallow_w, q_sh, nullptr, qshT, 1728, 3 };
    ta.d[1] = { tex_dw_w, q_tdw, nullptr, nullptr, 576, 0 };
    ta.d[2] = { tex_pw_w, q_tpw, nullptr, nullptr, 512, 0 };
    for (int i = 0; i < 8; i++)
        ta.d[3 + i]  = { exp_dw_w + i * 576,  q_edw + i * 576,  q_edw_h + i * 576,  nullptr, 576, 2 };
    for (int i = 0; i < 8; i++)
        ta.d[11 + i] = { exp_pw_w + i * 4096, q_epw + i * 4096, q_epw_h + i * 4096, nullptr, 4096, 1 };
    ta.d[19] = { ref1_w, q_r1, nullptr, nullptr, 81, 0 };
    ta.d[20] = { ref2_w, q_r2, nullptr, nullptr, 81, 0 };
    ternarize_kernel<<<22, 256, 0, stream>>>(ta, chans, recon_w, rwh);  // block 21: chans + recon Wt

    shallow_router_kernel<<<dim3(16, 16, 4), 512, 0, stream>>>(
        x, qshT, shallow_b, q_tdw, tex_dw_b, q_tpw, tex_pw_b, router_w, router_b,
        feat_h, top);

    if (merged) {
        expert_block_kernel<false><<<dim3(16, 16, 16), 512, 0, stream>>>(
            feat_h, q_edw_h, exp_dw_b, q_epw_h, exp_pw_b,
            A4, chans, nullptr, nullptr, nullptr, nullptr, 0, 2);
        y_kernel<<<16, 64, 0, stream>>>(chans, exp_fc1, exp_fc2, ysm_g, 0, 0);
        expert_block_kernel<true><<<dim3(16, 16, 16), 512, 0, stream>>>(
            A4, q_edw_h, exp_dw_b, q_epw_h, exp_pw_b,
            Bv_sh, chans, ysm_g, feat_h, Aap_sh, top, 0, 2);
    } else {
        for (int s = 0; s < 2; s++) {
            expert_block_kernel<false><<<dim3(16, 16, 8), 512, 0, stream>>>(
                feat_h, q_edw_h, exp_dw_b, q_epw_h, exp_pw_b,
                A4, chans, nullptr, nullptr, nullptr, nullptr, s * 2, 1);
            y_kernel<<<8, 64, 0, stream>>>(chans, exp_fc1, exp_fc2, ysm_g, s * 2, 0);
            expert_block_kernel<true><<<dim3(16, 16, 8), 512, 0, stream>>>(
                A4, q_edw_h, exp_dw_b, q_epw_h, exp_pw_b,
                Bv_sh, chans, ysm_g, feat_h, Aap_sh, top, s * 2, 1);
        }
    }
    y_kernel<<<16, 64, 0, stream>>>(chans, exp_fc1, exp_fc2, ysm_g, 0, 1);

    recon_kernel<<<dim3(16, 16, 4), 512, 0, stream>>>(Bv_sh, Aap_sh, top,
                                                      ysm_g, rwh, recon_b, x, srh);
    ref_fused_kernel<<<dim3(32, 32, 4), dim3(16, 16), 0, stream>>>(
        srh, q_r1, ref1_b, q_r2, ref2_b, (float*)d_out);
}

// Round 14
// 343.044 us; speedup vs baseline: 1.0230x; 1.0230x over previous
//
#include <hip/hip_runtime.h>
#include <hip/hip_fp16.h>
#include <math.h>

#define HW 65536            // 256*256
#define CHW 4194304         // 64*HW  (NHWC elements per batch)
#define BCHW 16777216
#define HW2 262144          // 512*512
#define TS 325              // tile pad stride (px) to break LDS conflicts

typedef _Float16 half8 __attribute__((ext_vector_type(8)));
typedef _Float16 half2v __attribute__((ext_vector_type(2)));
typedef float f32x4 __attribute__((ext_vector_type(4)));
typedef float f32x2 __attribute__((ext_vector_type(2)));

// XCD-locality tile mapping. Linearized wg id mod 8 == ibx&7 == XCD under
// round-robin dispatch. Map each XCD to 2 full tile-rows. Bijection 16x16.
__device__ __forceinline__ void swz16(int ibx, int iby, int& ox, int& oy) {
    oy = ((ibx & 7) << 1) | (ibx >> 3);
    ox = iby;
}

// chans layout: [8 layers][8 parts][4 b][64]  (parts indexed by ibx&7 = XCD)
#define CH_L 2048           // floats per layer (8 parts x 256)

// ---------------------------------------------------------------- ternarize
// mode: 0 = float only; 1 = + half linear; 2 = + half dw-transpose [tap][ci];
//       3 = + float transposed [k][64] (shallow conv, packed-f32 layout)
// block 21: zero chans + prepare recon Wt halves
struct TernDesc { const float* src; float* dst; __half* dsth; float* dstT; int n; int mode; };
struct TernArgs { TernDesc d[21]; };

__global__ __launch_bounds__(256) void ternarize_kernel(TernArgs args, float* __restrict__ chans,
                                                        const float* __restrict__ rw,
                                                        __half* __restrict__ rwh) {
    const int t = threadIdx.x;
    if (blockIdx.x == 21) {
        for (int i = t; i < 16384; i += 256) chans[i] = 0.f;
        for (int i = t; i < 10368; i += 256) {
            const int row = i / 72, ci = i - row * 72;
            const int tap = row >> 4, n = row & 15;
            rwh[i] = __float2half((ci < 64 && n < 12) ? rw[n * 576 + ci * 9 + tap] : 0.f);
        }
        return;
    }
    __shared__ float red[256];
    __shared__ float bc[2];
    TernDesc td = args.d[blockIdx.x];
    const int n = td.n;
    float s = 0.f;
    for (int i = t; i < n; i += 256) s += fabsf(td.src[i]);
    red[t] = s; __syncthreads();
    for (int k = 128; k > 0; k >>= 1) { if (t < k) red[t] += red[t + k]; __syncthreads(); }
    if (t == 0) bc[0] = 0.75f * red[0] / (float)n;
    __syncthreads();
    const float delta = bc[0];
    float s1 = 0.f, c1 = 0.f;
    for (int i = t; i < n; i += 256) {
        float a = fabsf(td.src[i]);
        if (a > delta) { s1 += a; c1 += 1.f; }
    }
    __syncthreads();
    red[t] = s1; __syncthreads();
    for (int k = 128; k > 0; k >>= 1) { if (t < k) red[t] += red[t + k]; __syncthreads(); }
    float sum1 = red[0];
    __syncthreads();
    red[t] = c1; __syncthreads();
    for (int k = 128; k > 0; k >>= 1) { if (t < k) red[t] += red[t + k]; __syncthreads(); }
    if (t == 0) bc[1] = sum1 / fmaxf(red[0], 1.f);
    __syncthreads();
    const float alpha = bc[1];
    for (int i = t; i < n; i += 256) {
        float w = td.src[i];
        const float q = (fabsf(w) > delta) ? ((w > 0.f) ? alpha : -alpha) : 0.f;
        td.dst[i] = q;
        if (td.mode == 1) td.dsth[i] = __float2half(q);
        else if (td.mode == 2) {
            const int ci = i / 9, tap = i - ci * 9;
            td.dsth[tap * 64 + ci] = __float2half(q);
        } else if (td.mode == 3) {
            const int co = i / 27, k = i - co * 27;
            td.dstT[k * 64 + co] = q;
        }
    }
}

// ---------------------------------------------------------------- y kernel: GAP->fc1->relu->fc2->sigmoid once per (expert, b)
__global__ __launch_bounds__(64) void y_kernel(const float* __restrict__ chans,
                                               const float* __restrict__ fc1b,
                                               const float* __restrict__ fc2b,
                                               __half* __restrict__ ysm_g,
                                               int ebase, int lbase) {
    __shared__ float csum[64];
    __shared__ float hid[16];
    const int t = threadIdx.x;
    const int e = ebase + (blockIdx.x >> 2), b = blockIdx.x & 3;
    const int li = e * 2 + lbase;
    {
        const float* cp = chans + li * CH_L + b * 64 + t;
        float s = 0.f;
#pragma unroll
        for (int p = 0; p < 8; p++) s += cp[p * 256];
        csum[t] = s;
    }
    __syncthreads();
    if (t < 16) {
        const float* fc1 = fc1b + li * 1024;
        float s = 0.f;
        for (int ci = 0; ci < 64; ci++) s = fmaf(fc1[t * 64 + ci], csum[ci], s);
        hid[t] = fmaxf(s, 0.f) * (1.f / 65536.f);
    }
    __syncthreads();
    {
        const float* fc2 = fc2b + li * 1024;
        float s = 0.f;
#pragma unroll
        for (int j = 0; j < 16; j++) s = fmaf(fc2[t * 16 + j], hid[j], s);
        ysm_g[li * 256 + b * 64 + t] = __float2half(1.f / (1.f + expf(-s)));
    }
}

// ---------------------------------------------------------------- fused shallow conv + texture encoder + router (512 thr)
// Shallow conv processes channel PAIRS via float2 (v_pk_fma_f32): weights
// arrive pre-transposed [k][64] (qshT). xs staged as f32x2 (pairs provably
// all-in/all-out of bounds: even column base). Bit-identical math.
__global__ __launch_bounds__(512, 6) void shallow_router_kernel(
    const float* __restrict__ x,
    const float* __restrict__ qshT, const float* __restrict__ shb,
    const float* __restrict__ qtdw, const float* __restrict__ tdwb,
    const float* __restrict__ qtpw, const float* __restrict__ tpwb,
    const float* __restrict__ rw,   const float* __restrict__ rbias,
    __half* __restrict__ feat_h, int* __restrict__ top) {
    __shared__ __align__(16) float xs[1200];          // [3][20][20]
    __shared__ __align__(16) float feats[324 * 36];   // [halo px][ch pad36]
    const int t = threadIdx.x;
    const int b = blockIdx.z;
    const int h0 = blockIdx.y * 16, w0 = blockIdx.x * 16;
    const float* xb = x + (size_t)b * 3 * HW;

    for (int i2 = t; i2 < 600; i2 += 512) {
        const int ci = i2 / 200, rem = i2 - ci * 200;
        const int ry = rem / 10, ux = rem - ry * 10;
        const int hh = h0 + ry - 2, wc = w0 + ux * 2 - 2;
        f32x2 v = {0.f, 0.f};
        if (hh >= 0 && hh < 256 && wc >= 0 && wc < 256)
            v = *(const f32x2*)&xb[ci * HW + hh * 256 + wc];
        *(f32x2*)&xs[ci * 400 + ry * 20 + ux * 2] = v;
    }
    float tex[8] = {0, 0, 0, 0, 0, 0, 0, 0};
    __half* fhb = feat_h + (size_t)b * CHW;
    __syncthreads();

    for (int pass = 0; pass < 2; pass++) {
        const int c0 = pass * 32;
        if (pass) __syncthreads();
        if (t < 324) {
            const int ry = t / 18, rx = t - ry * 18;
            float patch[27];
#pragma unroll
            for (int ci = 0; ci < 3; ci++)
#pragma unroll
                for (int dy = 0; dy < 3; dy++)
#pragma unroll
                    for (int dx = 0; dx < 3; dx++)
                        patch[ci * 9 + dy * 3 + dx] = xs[ci * 400 + (ry + dy) * 20 + rx + dx];
            for (int g = 0; g < 16; g++) {       // channel pairs (packed f32)
                const int co = c0 + g * 2;       // GLOBAL channel for weights
                f32x2 a2 = { shb[co], shb[co + 1] };
#pragma unroll
                for (int k = 0; k < 27; k++) {
                    const f32x2 w2 = *(const f32x2*)&qshT[k * 64 + co];
                    const f32x2 p2 = { patch[k], patch[k] };
                    a2 = __builtin_elementwise_fma(p2, w2, a2);
                }
                feats[t * 36 + g * 2]     = fmaxf(a2[0], 0.f);   // LOCAL LDS offset
                feats[t * 36 + g * 2 + 1] = fmaxf(a2[1], 0.f);
            }
        }
        __syncthreads();
        if (t < 256) {
            const int iy = t >> 4, ix = t & 15;
            for (int g = 0; g < 8; g++) {      // 4 channels per group, order preserved
                const int cl = g * 4;          // LOCAL channel offset in LDS row
                const int cb = c0 + cl;        // global channel for weights
                f32x4 o4;
#pragma unroll
                for (int c = 0; c < 4; c++) o4[c] = tdwb[cb + c];
#pragma unroll
                for (int dy = 0; dy < 3; dy++) {
                    const float* rowp = &feats[((iy + dy) * 18 + ix) * 36 + cl];
                    const f32x4 r0 = *(const f32x4*)&rowp[0];
                    const f32x4 r1 = *(const f32x4*)&rowp[36];
                    const f32x4 r2 = *(const f32x4*)&rowp[72];
                    f32x4 w0, w1, w2;
#pragma unroll
                    for (int c = 0; c < 4; c++) {
                        w0[c] = qtdw[(cb + c) * 9 + dy * 3];
                        w1[c] = qtdw[(cb + c) * 9 + dy * 3 + 1];
                        w2[c] = qtdw[(cb + c) * 9 + dy * 3 + 2];
                    }
                    // same chain as scalar: dx=2, then dx=1, then dx=0
                    o4 = __builtin_elementwise_fma(r2, w2, o4);
                    o4 = __builtin_elementwise_fma(r1, w1, o4);
                    o4 = __builtin_elementwise_fma(r0, w0, o4);
                }
#pragma unroll
                for (int c = 0; c < 4; c++) {
                    const float tc = fmaxf(o4[c], 0.f);
#pragma unroll
                    for (int j = 0; j < 8; j++)
                        tex[j] = fmaf(qtpw[j * 64 + cb + c], tc, tex[j]);
                }
            }
        } else {
            for (int id = t - 256; id < 1024; id += 256) {
                const int p = id >> 2, cg = id & 3;
                const int py = p >> 4, px = p & 15;
                const float* fp = &feats[((py + 1) * 18 + px + 1) * 36 + cg * 8];
                half8 pk;
#pragma unroll
                for (int j = 0; j < 8; j++) pk[j] = (_Float16)fp[j];
                *(half8*)&fhb[((size_t)((h0 + py) * 256 + w0 + px)) * 64 + c0 + cg * 8] = pk;
            }
        }
    }
    if (t < 256) {
        const int iy = t >> 4, ix = t & 15;
        float sgm[8];
#pragma unroll
        for (int j = 0; j < 8; j++) sgm[j] = 1.f / (1.f + expf(-(tex[j] + tpwb[j])));
        float best = -1e30f; int bi = 0;
#pragma unroll
        for (int e = 0; e < 4; e++) {
            float v = rbias[e];
#pragma unroll
            for (int j = 0; j < 8; j++) v = fmaf(rw[e * 8 + j], sgm[j], v);
            if (v > best) { best = v; bi = e; }     // first max (jnp.argmax)
        }
        top[(size_t)b * HW + (h0 + iy) * 256 + w0 + ix] = bi;
    }
}

// ---------------------------------------------------------------- expert block: 512 threads (r1/r11 structure)
template <bool APPLY>
__global__ __launch_bounds__(512, 4) void expert_block_kernel(
    const __half* __restrict__ in,
    const __half* __restrict__ qdwh_b, const float* __restrict__ dwb_b,
    const __half* __restrict__ qpwh_b, const float* __restrict__ pwb_b,
    __half* __restrict__ out_b, float* __restrict__ chans_b,
    const __half* __restrict__ ysm_g,
    const __half* __restrict__ F, __half* __restrict__ Aap,
    const int* __restrict__ topg, int ebase, int bshift) {
    __shared__ __align__(16) __half tile[8 * TS * 8];    // 41600 B; obuf/csb alias
    __shared__ __align__(16) __half wT[64 * 72];         // [co][ci pad72] 9216 B
    __shared__ __align__(16) __half wdwh[576];           // [tap][ci] 1152 B
    __shared__ __align__(16) _Float16 bdwh[64];
    __shared__ float bpw[64];
    __shared__ unsigned char topsm[256];
    const int t = threadIdx.x;
    const int z = blockIdx.z;
    const int b = z >> bshift, sub = z & ((1 << bshift) - 1);
    const int expert = ebase + sub;
    const int layer = expert * 2 + (APPLY ? 1 : 0);
    const int part = blockIdx.x & 7;                     // == XCD under round-robin
    const float* dwb = dwb_b + layer * 64;
    const float* pwb = pwb_b + layer * 64;
    float* chansum = chans_b + layer * CH_L + part * 256 + b * 64;
    int bx, by; swz16(blockIdx.x, blockIdx.y, bx, by);
    const int h0 = by * 16, w0 = bx * 16;

    {   // pw weights: 4096 halves = 512 threads x 1 half8
        const half8 w8 = *(const half8*)&qpwh_b[layer * 4096 + t * 8];
        *(half8*)&wT[(t >> 3) * 72 + (t & 7) * 8] = w8;
    }
    if (t < 72) *(half8*)&wdwh[t * 8] = *(const half8*)&qdwh_b[layer * 576 + t * 8];
    if (t < 64) { bdwh[t] = (_Float16)dwb[t]; bpw[t] = pwb[t]; }

    half8 y8h = {};
    if (APPLY) {
        if (t < 256)
            topsm[t] = (unsigned char)topg[(size_t)b * HW + (h0 + (t >> 4)) * 256 + w0 + (t & 15)];
        y8h = *(const half8*)&ysm_g[(expert * 2) * 256 + b * 64 + (t & 7) * 8];
        __syncthreads();    // topsm visible for routed A-store during staging
    }

    const __half* ib = (APPLY ? in + (size_t)sub * BCHW : in) + (size_t)b * CHW;
    const __half* Fb = APPLY ? (F + (size_t)b * CHW) : nullptr;
    __half* Ab = APPLY ? (Aap + (size_t)b * CHW) : nullptr;
    __half* ob = APPLY ? (out_b + (size_t)b * CHW)
                       : (out_b + (size_t)sub * BCHW + (size_t)b * CHW);

    // staging, force-unrolled: 5 full iterations + 32-thread tail
#pragma unroll
    for (int s = 0; s < 6; s++) {
        if (s < 5 || t < 32) {
            const int i = t + (s << 9);
            const int cg = i & 7;
            const int rem = i >> 3;            // 0..323
            const int ry = rem / 18, rx = rem - ry * 18;
            const int hh = h0 + ry - 1, ww = w0 + rx - 1;
            half8 v = {};
            if (hh >= 0 && hh < 256 && ww >= 0 && ww < 256) {
                const size_t off = (size_t)(hh * 256 + ww) * 64 + cg * 8;
                v = *(const half8*)&ib[off];
                if (APPLY) {
                    half8 f = *(const half8*)&Fb[off];
                    v = __builtin_elementwise_fma(v, y8h, f);
                    if (ry >= 1 && ry <= 16 && rx >= 1 && rx <= 16 &&
                        topsm[((ry - 1) << 4) + (rx - 1)] == expert)
                        *(half8*)&Ab[off] = v;
                }
            }
            *(half8*)&tile[(cg * TS + rem) * 8] = v;
        }
    }
    __syncthreads();

    const int lane = t & 63, wv = t >> 6;      // 8 waves, 2 rows each
    const int l15 = lane & 15, quad = lane >> 4;
    f32x4 acc[2][4];
#pragma unroll
    for (int i = 0; i < 2; i++)
#pragma unroll
        for (int j = 0; j < 4; j++) acc[i][j] = (f32x4){0.f, 0.f, 0.f, 0.f};

#pragma unroll
    for (int kh = 0; kh < 2; kh++) {
        const int cgk = kh * 4 + quad;
        half8 bf[4];
#pragma unroll
        for (int ct = 0; ct < 4; ct++)
            bf[ct] = *(const half8*)&wT[(ct * 16 + l15) * 72 + kh * 32 + quad * 8];
        half8 wv9[9];
#pragma unroll
        for (int tap = 0; tap < 9; tap++)
            wv9[tap] = *(const half8*)&wdwh[tap * 64 + kh * 32 + quad * 8];
        const half8 biash = *(const half8*)&bdwh[kh * 32 + quad * 8];
        // row-shared tap loads: rows wv*2..wv*2+3 (T=0 uses 0..2, T=1 uses 1..3)
        half8 xr[9];
#pragma unroll
        for (int dy = 0; dy < 3; dy++)
#pragma unroll
            for (int dx = 0; dx < 3; dx++)
                xr[dy * 3 + dx] = *(const half8*)&tile[(cgk * TS + (wv * 2 + dy) * 18 + (l15 + dx)) * 8];
#pragma unroll
        for (int T = 0; T < 2; T++) {
            if (T) {
#pragma unroll
                for (int q2 = 0; q2 < 6; q2++) xr[q2] = xr[q2 + 3];
#pragma unroll
                for (int dx = 0; dx < 3; dx++)
                    xr[6 + dx] = *(const half8*)&tile[(cgk * TS + (wv * 2 + 3) * 18 + (l15 + dx)) * 8];
            }
            // packed fp16 depthwise accumulate: 4x v_pk_fma_f16 per tap, no cvts
            half8 o8 = biash;
#pragma unroll
            for (int tap = 0; tap < 9; tap++)
                o8 = __builtin_elementwise_fma(xr[tap], wv9[tap], o8);
            const half8 zz = {};
            const half8 a = __builtin_elementwise_max(o8, zz);
#pragma unroll
            for (int ct = 0; ct < 4; ct++)
                acc[T][ct] = __builtin_amdgcn_mfma_f32_16x16x32_f16(a, bf[ct], acc[T][ct], 0, 0, 0);
        }
    }
    __syncthreads();   // tile reads done; alias obuf + csb onto tile

    __half* obuf = tile;                              // bytes 0..17407
    float* csb = (float*)((char*)tile + 20480);       // [8][64] floats
    __half* myo = &obuf[wv * 1088];
    float cs[4] = {0.f, 0.f, 0.f, 0.f};
    const int pxa = lane >> 3;
#pragma unroll
    for (int T = 0; T < 2; T++) {
        const int py_loc = wv * 2 + T;
#pragma unroll
        for (int ct = 0; ct < 4; ct++) {
            const float bv = bpw[ct * 16 + l15];
#pragma unroll
            for (int r = 0; r < 4; r++) {
                const float v = acc[T][ct][r] + bv;
                cs[ct] += v;
                myo[(quad * 4 + r) * 68 + ct * 16 + l15] = __float2half(v);
            }
        }
        const int py = h0 + py_loc;
        const size_t base = (size_t)(py * 256 + w0) * 64;
        half8 v0 = *(const half8*)&myo[pxa * 68 + (lane & 7) * 8];
        half8 v1 = *(const half8*)&myo[(8 + pxa) * 68 + (lane & 7) * 8];
        if (!APPLY || topsm[py_loc * 16 + pxa] == expert)
            *(half8*)&ob[base + lane * 8] = v0;
        if (!APPLY || topsm[py_loc * 16 + 8 + pxa] == expert)
            *(half8*)&ob[base + (lane + 64) * 8] = v1;
    }
#pragma unroll
    for (int ct = 0; ct < 4; ct++) {
        float s = cs[ct];
        s += __shfl_xor(s, 16);
        s += __shfl_xor(s, 32);
        if (quad == 0) csb[wv * 64 + ct * 16 + l15] = s;
    }
    __syncthreads();
    if (t < 64) {
        float s = 0.f;
#pragma unroll
        for (int w = 0; w < 8; w++) s += csb[w * 64 + t];
        atomicAdd(&chansum[t], s);
    }
}

// ---------------------------------------------------------------- bilinear x2 upsample from an 18x18 LDS region
__device__ __forceinline__ float bilin_lds(const float* __restrict__ xr,
                                           int h0, int w0, int h, int w, int r1, int r2) {
    int hlo, hhi; float wrr;
    if (r1 == 0) { hlo = h - 1; hhi = h;     wrr = 0.25f; }
    else         { hlo = h;     hhi = h + 1; wrr = 0.75f; }
    if (hlo < 0)   { hlo = 0;   wrr = 0.f; }
    if (hhi > 255) { hhi = 255; wrr = 1.f; }
    int wlo, whi; float wcc;
    if (r2 == 0) { wlo = w - 1; whi = w;     wcc = 0.25f; }
    else         { wlo = w;     whi = w + 1; wcc = 0.75f; }
    if (wlo < 0)   { wlo = 0;   wcc = 0.f; }
    if (whi > 255) { whi = 255; wcc = 1.f; }
    const int rl = hlo - (h0 - 1), rh = hhi - (h0 - 1);
    const int cl = wlo - (w0 - 1), ch = whi - (w0 - 1);
    const float a = xr[rl * 18 + cl] * wcc + xr[rl * 18 + ch] * (1.f - wcc);
    const float b = xr[rh * 18 + cl] * wcc + xr[rh * 18 + ch] * (1.f - wcc);
    return a * wrr + b * (1.f - wrr);
}

// ---------------------------------------------------------------- recon (512 thr) fused select; y1 precomputed; x + top staged in LDS
__global__ __launch_bounds__(512, 4) void recon_kernel(const __half* __restrict__ Bv,
                                                       const __half* __restrict__ Aap,
                                                       const int* __restrict__ topg,
                                                       const __half* __restrict__ ysm_g,
                                                       const __half* __restrict__ rwh,  // [9*16][72] halves
                                                       const float* __restrict__ rbias,
                                                       const float* __restrict__ x,
                                                       __half* __restrict__ srh) {
    __shared__ __align__(16) __half tile[8 * TS * 8];     // 41600 B
    __shared__ __align__(16) __half Wt[9 * 16 * 72];      // 20736 B
    __shared__ float xls[3 * 324];                        // [3][18][18] clamped x region
    __shared__ int topls[324];                            // top halo (OOB -> 0)
    __shared__ float bsm12[12];
    __shared__ __align__(16) _Float16 ysmh[4][64];
    const int t = threadIdx.x;
    const int b = blockIdx.z;
    int bx, by; swz16(blockIdx.x, blockIdx.y, bx, by);
    const int h0 = by * 16, w0 = bx * 16;
    const int* tb = topg + (size_t)b * HW;

    for (int i = t; i < 1296; i += 512)
        *(half8*)&Wt[i * 8] = *(const half8*)&rwh[i * 8];
    {   // stage clamped 18x18x3 x region (coalesced, 2 rounds)
        const float* xb3 = x + (size_t)b * 3 * HW;
        for (int i = t; i < 972; i += 512) {
            const int ci = i / 324, rem = i - ci * 324;
            const int ry = rem / 18, rx = rem - ry * 18;
            const int gh = min(max(h0 - 1 + ry, 0), 255);
            const int gw = min(max(w0 - 1 + rx, 0), 255);
            xls[i] = xb3[ci * HW + gh * 256 + gw];
        }
    }
    if (t < 324) {  // stage top halo once (8 channel groups reuse it)
        const int ry = t / 18, rx = t - ry * 18;
        const int hh = h0 + ry - 1, ww = w0 + rx - 1;
        topls[t] = (hh >= 0 && hh < 256 && ww >= 0 && ww < 256) ? tb[hh * 256 + ww] : 0;
    }
    if (t < 12) bsm12[t] = rbias[t];
    if (t >= 480) {   // y1 for the 4 experts (precomputed by y_kernel)
        const int u = t - 480, e = u >> 3;
        *(half8*)&ysmh[e][(u & 7) * 8] =
            *(const half8*)&ysm_g[(e * 2 + 1) * 256 + b * 64 + (u & 7) * 8];
    }
    __syncthreads();    // ysmh + Wt + xls + topls ready

    const __half* bb = Bv + (size_t)b * CHW;
    const __half* ab = Aap + (size_t)b * CHW;

#pragma unroll
    for (int s = 0; s < 6; s++) {
        if (s < 5 || t < 32) {
            const int i = t + (s << 9);
            const int cg = i & 7;
            const int rem = i >> 3;
            const int ry = rem / 18, rx = rem - ry * 18;
            const int hh = h0 + ry - 1, ww = w0 + rx - 1;
            half8 v = {};
            if (hh >= 0 && hh < 256 && ww >= 0 && ww < 256) {
                const size_t off = (size_t)(hh * 256 + ww) * 64 + cg * 8;
                half8 bv8 = *(const half8*)&bb[off];
                half8 av8 = *(const half8*)&ab[off];
                const int e = topls[rem];
                half8 yv = *(const half8*)&ysmh[e][cg * 8];
                v = __builtin_elementwise_fma(bv8, yv, av8);
            }
            *(half8*)&tile[(cg * TS + rem) * 8] = v;
        }
    }
    __syncthreads();

    const int lane = t & 63, wvi = t >> 6;
    const int l15 = lane & 15, quad = lane >> 4;
    f32x4 acc[2];
#pragma unroll
    for (int i = 0; i < 2; i++) acc[i] = (f32x4){0.f, 0.f, 0.f, 0.f};

#pragma unroll
    for (int kh = 0; kh < 2; kh++) {
        const int cgk = kh * 4 + quad;
        half8 bf[9];
#pragma unroll
        for (int tap = 0; tap < 9; tap++)
            bf[tap] = *(const half8*)&Wt[(tap * 16 + l15) * 72 + kh * 32 + quad * 8];
        // row-shared tap loads
        half8 xr[9];
#pragma unroll
        for (int dy = 0; dy < 3; dy++)
#pragma unroll
            for (int dx = 0; dx < 3; dx++)
                xr[dy * 3 + dx] = *(const half8*)&tile[(cgk * TS + (wvi * 2 + dy) * 18 + (l15 + dx)) * 8];
#pragma unroll
        for (int T = 0; T < 2; T++) {
            if (T) {
#pragma unroll
                for (int q2 = 0; q2 < 6; q2++) xr[q2] = xr[q2 + 3];
#pragma unroll
                for (int dx = 0; dx < 3; dx++)
                    xr[6 + dx] = *(const half8*)&tile[(cgk * TS + (wvi * 2 + 3) * 18 + (l15 + dx)) * 8];
            }
#pragma unroll
            for (int tap = 0; tap < 9; tap++)
                acc[T] = __builtin_amdgcn_mfma_f32_16x16x32_f16(xr[tap], bf[tap], acc[T], 0, 0, 0);
        }
    }
    if (l15 < 12) {
        const int c = l15 >> 2, r1 = (l15 >> 1) & 1, r2 = l15 & 1;
        const float* xreg = &xls[c * 324];
        const float bv = bsm12[l15];
        __half* sb = srh + ((size_t)b * 3 + c) * HW2;
#pragma unroll
        for (int T = 0; T < 2; T++) {
            const int py = h0 + wvi * 2 + T;
#pragma unroll
            for (int r = 0; r < 4; r++) {
                const int wglob = w0 + quad * 4 + r;
                const float xu = bilin_lds(xreg, h0, w0, py, wglob, r1, r2);
                sb[(2 * py + r1) * 512 + 2 * wglob + r2] = __float2half(acc[T][r] + bv + xu);
            }
        }
    }
}

// ---------------------------------------------------------------- fused refinement: out = sr + conv2(relu(conv1(sr))); fp16 sr in
// sr staging via half2 (pairs are all-in/all-out of bounds: even column base)
__global__ __launch_bounds__(256) void ref_fused_kernel(const __half* __restrict__ in,  // sr half [4][3][512][512]
                                                        const float* __restrict__ q1,
                                                        const float* __restrict__ b1,
                                                        const float* __restrict__ q2,
                                                        const float* __restrict__ b2,
                                                        float* __restrict__ outp) {
    __shared__ float srs[1200];       // [3][20][20] halo ±2
    __shared__ float t1s[3 * 324];    // [3][18][18] halo ±1
    __shared__ float w1[81], w2[81];
    __shared__ float bb1[3], bb2[3];
    const int t = threadIdx.y * 16 + threadIdx.x;
    const int b = blockIdx.z;
    const int h0 = blockIdx.y * 16, w0 = blockIdx.x * 16;
    if (t < 81) { w1[t] = q1[t]; w2[t] = q2[t]; }
    if (t < 3)  { bb1[t] = b1[t]; bb2[t] = b2[t]; }
    for (int i2 = t; i2 < 600; i2 += 256) {
        const int ci = i2 / 200, rem = i2 - ci * 200;
        const int ry = rem / 10, ux = rem - ry * 10;
        const int hh = h0 + ry - 2, wc = w0 + ux * 2 - 2;
        float v0 = 0.f, v1 = 0.f;
        if (hh >= 0 && hh < 512 && wc >= 0 && wc < 512) {
            const half2v p = *(const half2v*)&in[((size_t)b * 3 + ci) * HW2 + hh * 512 + wc];
            v0 = (float)p[0]; v1 = (float)p[1];
        }
        srs[ci * 400 + ry * 20 + ux * 2] = v0;
        srs[ci * 400 + ry * 20 + ux * 2 + 1] = v1;
    }
    __syncthreads();
    for (int p = t; p < 324; p += 256) {
        const int ry = p / 18, rx = p - ry * 18;
        const int ih = h0 + ry - 1, iw = w0 + rx - 1;
        const bool valid = (ih >= 0 && ih < 512 && iw >= 0 && iw < 512);
#pragma unroll
        for (int o = 0; o < 3; o++) {
            float a = 0.f;
#pragma unroll
            for (int ci = 0; ci < 3; ci++) {
                const float* wp = &w1[o * 27 + ci * 9];
                const float* sp = &srs[ci * 400 + ry * 20 + rx];
#pragma unroll
                for (int ky = 0; ky < 3; ky++)
#pragma unroll
                    for (int kx = 0; kx < 3; kx++)
                        a = fmaf(sp[ky * 20 + kx], wp[ky * 3 + kx], a);
            }
            t1s[o * 324 + p] = valid ? fmaxf(a + bb1[o], 0.f) : 0.f;
        }
    }
    __syncthreads();
    const int ty = threadIdx.y, tx = threadIdx.x;
#pragma unroll
    for (int o = 0; o < 3; o++) {
        float a = 0.f;
#pragma unroll
        for (int ci = 0; ci < 3; ci++) {
            const float* wp = &w2[o * 27 + ci * 9];
            const float* tp = &t1s[ci * 324 + ty * 18 + tx];
#pragma unroll
            for (int ky = 0; ky < 3; ky++)
#pragma unroll
                for (int kx = 0; kx < 3; kx++)
                    a = fmaf(tp[ky * 18 + kx], wp[ky * 3 + kx], a);
        }
        const float v = a + bb2[o] + srs[o * 400 + (ty + 2) * 20 + tx + 2];
        outp[((size_t)b * 3 + o) * HW2 + (h0 + ty) * 512 + w0 + tx] = v;
    }
}

// ---------------------------------------------------------------- launcher
extern "C" void kernel_launch(void* const* d_in, const int* in_sizes, int n_in,
                              void* d_out, int out_size, void* d_ws, size_t ws_size,
                              hipStream_t stream) {
    const float* x         = (const float*)d_in[0];
    const float* shallow_w = (const float*)d_in[1];
    const float* shallow_b = (const float*)d_in[2];
    const float* tex_dw_w  = (const float*)d_in[3];
    const float* tex_dw_b  = (const float*)d_in[4];
    const float* tex_pw_w  = (const float*)d_in[5];
    const float* tex_pw_b  = (const float*)d_in[6];
    const float* router_w  = (const float*)d_in[7];
    const float* router_b  = (const float*)d_in[8];
    const float* exp_dw_w  = (const float*)d_in[9];
    const float* exp_dw_b  = (const float*)d_in[10];
    const float* exp_pw_w  = (const float*)d_in[11];
    const float* exp_pw_b  = (const float*)d_in[12];
    const float* exp_fc1   = (const float*)d_in[13];
    const float* exp_fc2   = (const float*)d_in[14];
    const float* recon_w   = (const float*)d_in[15];
    const float* recon_b   = (const float*)d_in[16];
    const float* ref1_w    = (const float*)d_in[17];
    const float* ref1_b    = (const float*)d_in[18];
    const float* ref2_w    = (const float*)d_in[19];
    const float* ref2_b    = (const float*)d_in[20];

    // mode: merged (all 4 experts per dispatch, 4 A-slots) if workspace allows
    const size_t need_merged = 237000000ULL;
    const bool merged = (ws_size >= need_merged);
    const int nslot = merged ? 4 : 2;

    __half* feat_h = (__half*)d_ws;                      // 32 MB
    __half* A4     = feat_h + BCHW;                      // nslot x 32 MB
    __half* Bv_sh  = A4 + (size_t)nslot * BCHW;          // 32 MB, routed-shared
    __half* Aap_sh = Bv_sh + BCHW;                       // 32 MB, routed-shared
    int*    top    = (int*)(Aap_sh + BCHW);              // 1 MB
    __half* q_edw_h = (__half*)(top + 262144);           // 8*576 halves (16B aligned)
    __half* q_epw_h = q_edw_h + 4608;                    // 8*4096 halves
    __half* rwh     = q_epw_h + 32768;                   // 10368 halves (recon Wt)
    __half* ysm_g   = rwh + 10368;                       // 2048 halves (y per layer,b)
    float*  qb     = (float*)(ysm_g + 2048);
    float*  q_sh   = qb;                 // 1728 (linear float, unused by kernels)
    float*  q_tdw  = q_sh + 1728;        // 576
    float*  q_tpw  = q_tdw + 576;        // 512
    float*  q_edw  = q_tpw + 512;        // 8*576 (float copy, unused by kernels)
    float*  q_epw  = q_edw + 4608;       // 8*4096 (float copy, unused by kernels)
    float*  q_r1   = q_epw + 32768;      // 81
    float*  q_r2   = q_r1 + 81;          // 81
    float*  chans  = q_r2 + 81;          // 8 layers x 8 parts x 256 = 16384
    float*  qshT   = chans + 16384;      // 27*64 transposed shallow weights
    __half* srh    = (__half*)A4;        // 25 MB as half (A4 dead after last APPLY)

    TernArgs ta;
    ta.d[0] = { shallow_w, q_sh, nullptr, qshT, 1728, 3 };
    ta.d[1] = { tex_dw_w, q_tdw, nullptr, nullptr, 576, 0 };
    ta.d[2] = { tex_pw_w, q_tpw, nullptr, nullptr, 512, 0 };
    for (int i = 0; i < 8; i++)
        ta.d[3 + i]  = { exp_dw_w + i * 576,  q_edw + i * 576,  q_edw_h + i * 576,  nullptr, 576, 2 };
    for (int i = 0; i < 8; i++)
        ta.d[11 + i] = { exp_pw_w + i * 4096, q_epw + i * 4096, q_epw_h + i * 4096, nullptr, 4096, 1 };
    ta.d[19] = { ref1_w, q_r1, nullptr, nullptr, 81, 0 };
    ta.d[20] = { ref2_w, q_r2, nullptr, nullptr, 81, 0 };
    ternarize_kernel<<<22, 256, 0, stream>>>(ta, chans, recon_w, rwh);  // block 21: chans + recon Wt

    shallow_router_kernel<<<dim3(16, 16, 4), 512, 0, stream>>>(
        x, qshT, shallow_b, q_tdw, tex_dw_b, q_tpw, tex_pw_b, router_w, router_b,
        feat_h, top);

    if (merged) {
        expert_block_kernel<false><<<dim3(16, 16, 16), 512, 0, stream>>>(
            feat_h, q_edw_h, exp_dw_b, q_epw_h, exp_pw_b,
            A4, chans, nullptr, nullptr, nullptr, nullptr, 0, 2);
        y_kernel<<<16, 64, 0, stream>>>(chans, exp_fc1, exp_fc2, ysm_g, 0, 0);
        expert_block_kernel<true><<<dim3(16, 16, 16), 512, 0, stream>>>(
            A4, q_edw_h, exp_dw_b, q_epw_h, exp_pw_b,
            Bv_sh, chans, ysm_g, feat_h, Aap_sh, top, 0, 2);
    } else {
        for (int s = 0; s < 2; s++) {
            expert_block_kernel<false><<<dim3(16, 16, 8), 512, 0, stream>>>(
                feat_h, q_edw_h, exp_dw_b, q_epw_h, exp_pw_b,
                A4, chans, nullptr, nullptr, nullptr, nullptr, s * 2, 1);
            y_kernel<<<8, 64, 0, stream>>>(chans, exp_fc1, exp_fc2, ysm_g, s * 2, 0);
            expert_block_kernel<true><<<dim3(16, 16, 8), 512, 0, stream>>>(
                A4, q_edw_h, exp_dw_b, q_epw_h, exp_pw_b,
                Bv_sh, chans, ysm_g, feat_h, Aap_sh, top, s * 2, 1);
        }
    }
    y_kernel<<<16, 64, 0, stream>>>(chans, exp_fc1, exp_fc2, ysm_g, 0, 1);

    recon_kernel<<<dim3(16, 16, 4), 512, 0, stream>>>(Bv_sh, Aap_sh, top,
                                                      ysm_g, rwh, recon_b, x, srh);
    ref_fused_kernel<<<dim3(32, 32, 4), dim3(16, 16), 0, stream>>>(
        srh, q_r1, ref1_b, q_r2, ref2_b, (float*)d_out);
}